// Round 1
// baseline (53.987 us; speedup 1.0000x reference)
//
#include <hip/hip_runtime.h>
#include <math.h>

#define BATCH 8
#define NPRED 4096
#define MGT   2048
#define UU    4096
#define MTILE 1024   // gt boxes staged per block
#define NTILE 256    // pred boxes per block (== blockDim)

__global__ __launch_bounds__(256) void iou_max_kernel(
    const float4* __restrict__ pred_boxes,   // [B*N] xyxy
    const int*    __restrict__ pred_classes, // [B*N]
    const float4* __restrict__ gt_boxes,     // [B*M] xyxy
    float* __restrict__ ws)                  // [256] per-block maxima
{
    __shared__ float gx1[MTILE], gy1[MTILE], gx2[MTILE], gy2[MTILE], ga[MTILE];
    __shared__ float wmax[4];

    const int tid = threadIdx.x;
    const int blk = blockIdx.x;           // 0..255
    const int b      = blk >> 5;          // 32 blocks per batch
    const int sub    = blk & 31;
    const int nchunk = sub >> 1;          // 0..15
    const int mchunk = sub & 1;           // 0..1

    // stage gt tile into LDS, precompute gt areas
    const int mbase = b * MGT + mchunk * MTILE;
    for (int m = tid; m < MTILE; m += NTILE) {
        float4 g = gt_boxes[mbase + m];
        gx1[m] = g.x; gy1[m] = g.y; gx2[m] = g.z; gy2[m] = g.w;
        ga[m]  = (g.z - g.x) * (g.w - g.y);
    }
    __syncthreads();

    const int n = nchunk * NTILE + tid;
    const float4 p = pred_boxes[b * NPRED + n];
    const bool person = (pred_classes[b * NPRED + n] == 0);
    const float area_p = (p.z - p.x) * (p.w - p.y);

    float best = 0.0f;
    #pragma unroll 8
    for (int m = 0; m < MTILE; ++m) {
        // LDS reads below are wave-uniform (m uniform) -> broadcast, no conflicts
        float iw = fminf(p.z, gx2[m]) - fmaxf(p.x, gx1[m]);
        float ih = fminf(p.w, gy2[m]) - fmaxf(p.y, gy1[m]);
        iw = fmaxf(iw, 0.0f);
        ih = fmaxf(ih, 0.0f);
        float inter = iw * ih;
        float uni   = area_p + ga[m] - inter;
        float iou   = inter * __builtin_amdgcn_rcpf(fmaxf(uni, 1e-9f));
        best = fmaxf(best, iou);
    }
    if (!person) best = 0.0f;   // non-person preds contribute 0 (matches masked ref)

    // wave(64) max reduce
    #pragma unroll
    for (int off = 32; off >= 1; off >>= 1)
        best = fmaxf(best, __shfl_xor(best, off));
    if ((tid & 63) == 0) wmax[tid >> 6] = best;
    __syncthreads();
    if (tid == 0)
        ws[blk] = fmaxf(fmaxf(wmax[0], wmax[1]), fmaxf(wmax[2], wmax[3]));
}

__global__ __launch_bounds__(256) void finalize_kernel(
    const float* __restrict__ ws,            // [256] block maxima (32 per batch)
    const float* __restrict__ union_scores,  // [U]
    const int*   __restrict__ union_classes, // [U]
    float* __restrict__ out)                 // [2] = {max_prob_t, max_iou_t}
{
    __shared__ float smem[8];    // per-batch iou maxima
    __shared__ float pmax[4];    // per-wave prob maxima
    const int tid = threadIdx.x;

    // --- max prob over union entries with class 0 ---
    float mp = -INFINITY;
    for (int u = tid; u < UU; u += 256)
        if (union_classes[u] == 0) mp = fmaxf(mp, union_scores[u]);
    #pragma unroll
    for (int off = 32; off >= 1; off >>= 1)
        mp = fmaxf(mp, __shfl_xor(mp, off));
    if ((tid & 63) == 0) pmax[tid >> 6] = mp;

    // --- per-batch iou max: 32 consecutive ws slots per batch ---
    float v = ws[tid];
    #pragma unroll
    for (int off = 16; off >= 1; off >>= 1)
        v = fmaxf(v, __shfl_xor(v, off, 32));  // reduce within 32-lane groups
    if ((tid & 31) == 0) smem[tid >> 5] = v;
    __syncthreads();

    if (tid == 0) {
        float s = 0.0f;
        #pragma unroll
        for (int i = 0; i < 8; ++i) s += smem[i];
        out[1] = s * (1.0f / 8.0f);   // max_iou_t (mean over batches)
        out[0] = fmaxf(fmaxf(pmax[0], pmax[1]), fmaxf(pmax[2], pmax[3])); // max_prob_t
    }
}

extern "C" void kernel_launch(void* const* d_in, const int* in_sizes, int n_in,
                              void* d_out, int out_size, void* d_ws, size_t ws_size,
                              hipStream_t stream) {
    const float4* pred_boxes    = (const float4*)d_in[0];
    // d_in[1] = pred_scores (unused by the reference result)
    const int*    pred_classes  = (const int*)d_in[2];
    const float4* gt_boxes      = (const float4*)d_in[3];
    const float*  union_scores  = (const float*)d_in[4];
    const int*    union_classes = (const int*)d_in[5];
    float* out = (float*)d_out;
    float* ws  = (float*)d_ws;   // 256 floats, every slot written each call

    iou_max_kernel<<<256, 256, 0, stream>>>(pred_boxes, pred_classes, gt_boxes, ws);
    finalize_kernel<<<1, 256, 0, stream>>>(ws, union_scores, union_classes, out);
}

// Round 2
// 17.105 us; speedup vs baseline: 3.1562x; 3.1562x over previous
//
#include <hip/hip_runtime.h>
#include <math.h>

#define BATCH 8
#define NPRED 4096
#define MGT   2048
#define UU    4096
#define GTBLK 256
#define NBLK  (BATCH * (MGT / GTBLK))   // 64 blocks
#define CHUNK 2048                      // preds compacted per pass (worst-case safe)
#define NCHUNK (NPRED / CHUNK)          // 2

__global__ __launch_bounds__(256) void iou_person_kernel(
    const float4* __restrict__ pred_boxes,    // [B*N]
    const int4*   __restrict__ pred_classes4, // [B*N/4]
    const float4* __restrict__ gt_boxes,      // [B*M]
    float* __restrict__ ws)                   // [64] per-block maxima
{
    __shared__ float4 plist[CHUNK];   // compacted person boxes
    __shared__ float  parea[CHUNK];
    __shared__ int    lcount;
    __shared__ float  wmax[4];

    const int tid = threadIdx.x;
    const int blk = blockIdx.x;       // 0..63
    const int b    = blk >> 3;        // batch
    const int gsub = blk & 7;         // gt slice

    // this thread's gt box (registers); zeroed invalid gts give iou=0 naturally
    const float4 g = gt_boxes[b * MGT + gsub * GTBLK + tid];
    const float area_g = (g.z - g.x) * (g.w - g.y);

    float best = 0.0f;

    for (int c = 0; c < NCHUNK; ++c) {
        if (tid == 0) lcount = 0;
        __syncthreads();

        // --- compact person preds from this chunk into LDS ---
        #pragma unroll
        for (int s = 0; s < CHUNK / (256 * 4); ++s) {   // 2 sub-steps
            const int i4 = (b * NPRED + c * CHUNK) / 4 + s * 256 + tid;
            const int4 cl = pred_classes4[i4];
            const int pb = i4 * 4;
            if (cl.x == 0) { int p = atomicAdd(&lcount, 1); float4 bx = pred_boxes[pb + 0]; plist[p] = bx; parea[p] = (bx.z - bx.x) * (bx.w - bx.y); }
            if (cl.y == 0) { int p = atomicAdd(&lcount, 1); float4 bx = pred_boxes[pb + 1]; plist[p] = bx; parea[p] = (bx.z - bx.x) * (bx.w - bx.y); }
            if (cl.z == 0) { int p = atomicAdd(&lcount, 1); float4 bx = pred_boxes[pb + 2]; plist[p] = bx; parea[p] = (bx.z - bx.x) * (bx.w - bx.y); }
            if (cl.w == 0) { int p = atomicAdd(&lcount, 1); float4 bx = pred_boxes[pb + 3]; plist[p] = bx; parea[p] = (bx.z - bx.x) * (bx.w - bx.y); }
        }
        __syncthreads();

        // --- each thread: its gt vs all persons in this chunk ---
        const int cnt = lcount;       // uniform; LDS reads below are broadcasts
        #pragma unroll 4
        for (int j = 0; j < cnt; ++j) {
            const float4 p = plist[j];
            const float ap = parea[j];
            float iw = fminf(p.z, g.z) - fmaxf(p.x, g.x);
            float ih = fminf(p.w, g.w) - fmaxf(p.y, g.y);
            iw = fmaxf(iw, 0.0f);
            ih = fmaxf(ih, 0.0f);
            const float inter = iw * ih;
            const float uni   = ap + area_g - inter;
            const float iou   = inter * __builtin_amdgcn_rcpf(fmaxf(uni, 1e-9f));
            best = fmaxf(best, iou);
        }
        __syncthreads();              // protect lcount/plist before next chunk
    }

    // block max reduce
    #pragma unroll
    for (int off = 32; off >= 1; off >>= 1)
        best = fmaxf(best, __shfl_xor(best, off));
    if ((tid & 63) == 0) wmax[tid >> 6] = best;
    __syncthreads();
    if (tid == 0)
        ws[blk] = fmaxf(fmaxf(wmax[0], wmax[1]), fmaxf(wmax[2], wmax[3]));
}

__global__ __launch_bounds__(256) void finalize_kernel(
    const float* __restrict__ ws,            // [64] block maxima (8 per batch)
    const float* __restrict__ union_scores,  // [U]
    const int*   __restrict__ union_classes, // [U]
    float* __restrict__ out)                 // [2] = {max_prob_t, max_iou_t}
{
    __shared__ float smem[8];
    __shared__ float pmax[4];
    const int tid = threadIdx.x;

    // masked max over union entries
    float mp = -INFINITY;
    for (int u = tid; u < UU; u += 256)
        if (union_classes[u] == 0) mp = fmaxf(mp, union_scores[u]);
    #pragma unroll
    for (int off = 32; off >= 1; off >>= 1)
        mp = fmaxf(mp, __shfl_xor(mp, off));
    if ((tid & 63) == 0) pmax[tid >> 6] = mp;

    // per-batch iou max: 8 consecutive ws slots per batch (tid<64 covers all)
    float v = (tid < 64) ? ws[tid] : 0.0f;
    #pragma unroll
    for (int off = 4; off >= 1; off >>= 1)
        v = fmaxf(v, __shfl_xor(v, off, 8));
    if (tid < 64 && (tid & 7) == 0) smem[tid >> 3] = v;
    __syncthreads();

    if (tid == 0) {
        float s = 0.0f;
        #pragma unroll
        for (int i = 0; i < 8; ++i) s += smem[i];
        out[1] = s * 0.125f;  // mean over batches
        out[0] = fmaxf(fmaxf(pmax[0], pmax[1]), fmaxf(pmax[2], pmax[3]));
    }
}

extern "C" void kernel_launch(void* const* d_in, const int* in_sizes, int n_in,
                              void* d_out, int out_size, void* d_ws, size_t ws_size,
                              hipStream_t stream) {
    const float4* pred_boxes    = (const float4*)d_in[0];
    // d_in[1] = pred_scores (unused by the reference result)
    const int4*   pred_classes4 = (const int4*)d_in[2];
    const float4* gt_boxes      = (const float4*)d_in[3];
    const float*  union_scores  = (const float*)d_in[4];
    const int*    union_classes = (const int*)d_in[5];
    float* out = (float*)d_out;
    float* ws  = (float*)d_ws;   // 64 floats, every slot written each call

    iou_person_kernel<<<NBLK, 256, 0, stream>>>(pred_boxes, pred_classes4, gt_boxes, ws);
    finalize_kernel<<<1, 256, 0, stream>>>(ws, union_scores, union_classes, out);
}

// Round 3
// 14.889 us; speedup vs baseline: 3.6261x; 1.1489x over previous
//
#include <hip/hip_runtime.h>
#include <math.h>

#define BATCH  8
#define NPRED  4096
#define MGT    2048
#define UU     4096
#define CHUNK  2048                 // preds compacted per pass (worst-case safe in LDS)
#define NCHUNK (NPRED / CHUNK)      // 2
#define GPB    4                    // gt-slice blocks per batch
#define NSLOT  (BATCH * GPB)        // 32 handshake slots
#define GTS    (MGT / GPB)          // 512 gts per block
#define MAGIC  0xC0FFEE00u

__global__ __launch_bounds__(256) void fused_kernel(
    const float4* __restrict__ pred_boxes,     // [B*N]
    const int4*   __restrict__ pred_classes4,  // [B*N/4]
    const float4* __restrict__ gt_boxes,       // [B*M]
    const float4* __restrict__ union_scores4,  // [U/4]
    const int4*   __restrict__ union_classes4, // [U/4]
    unsigned long long* __restrict__ slots,    // ws: 32 x u64 handshake words
    float* __restrict__ out)                   // [2] = {max_prob_t, max_iou_t}
{
    const int tid = threadIdx.x;
    const int blk = blockIdx.x;

    if (blk < NSLOT) {
        // ---------------- per-(batch, gt-slice) block ----------------
        __shared__ float4 plist[CHUNK];
        __shared__ float  parea[CHUNK];
        __shared__ int    lcount;
        __shared__ float  wmax[4];

        const int b    = blk >> 2;
        const int gsub = blk & 3;

        // 2 gt boxes per thread, in registers (coalesced loads)
        const float4 g0 = gt_boxes[b * MGT + gsub * GTS + tid];
        const float4 g1 = gt_boxes[b * MGT + gsub * GTS + 256 + tid];
        const float  a0 = (g0.z - g0.x) * (g0.w - g0.y);
        const float  a1 = (g1.z - g1.x) * (g1.w - g1.y);

        float best = 0.0f;

        for (int c = 0; c < NCHUNK; ++c) {
            if (tid == 0) lcount = 0;
            __syncthreads();

            // compact person preds of this chunk into LDS
            #pragma unroll
            for (int s = 0; s < CHUNK / (256 * 4); ++s) {   // 2 sub-steps
                const int i4 = (b * NPRED + c * CHUNK) / 4 + s * 256 + tid;
                const int4 cl = pred_classes4[i4];
                const int pb = i4 * 4;
                if (cl.x == 0) { int p = atomicAdd(&lcount, 1); float4 bx = pred_boxes[pb + 0]; plist[p] = bx; parea[p] = (bx.z - bx.x) * (bx.w - bx.y); }
                if (cl.y == 0) { int p = atomicAdd(&lcount, 1); float4 bx = pred_boxes[pb + 1]; plist[p] = bx; parea[p] = (bx.z - bx.x) * (bx.w - bx.y); }
                if (cl.z == 0) { int p = atomicAdd(&lcount, 1); float4 bx = pred_boxes[pb + 2]; plist[p] = bx; parea[p] = (bx.z - bx.x) * (bx.w - bx.y); }
                if (cl.w == 0) { int p = atomicAdd(&lcount, 1); float4 bx = pred_boxes[pb + 3]; plist[p] = bx; parea[p] = (bx.z - bx.x) * (bx.w - bx.y); }
            }
            __syncthreads();

            const int cnt = lcount;   // uniform -> LDS broadcasts below
            for (int j = 0; j < cnt; ++j) {
                const float4 p = plist[j];
                const float  ap = parea[j];
                {
                    float iw = fminf(p.z, g0.z) - fmaxf(p.x, g0.x);
                    float ih = fminf(p.w, g0.w) - fmaxf(p.y, g0.y);
                    iw = fmaxf(iw, 0.0f); ih = fmaxf(ih, 0.0f);
                    const float inter = iw * ih;
                    const float uni   = ap + a0 - inter;
                    best = fmaxf(best, inter * __builtin_amdgcn_rcpf(fmaxf(uni, 1e-9f)));
                }
                {
                    float iw = fminf(p.z, g1.z) - fmaxf(p.x, g1.x);
                    float ih = fminf(p.w, g1.w) - fmaxf(p.y, g1.y);
                    iw = fmaxf(iw, 0.0f); ih = fmaxf(ih, 0.0f);
                    const float inter = iw * ih;
                    const float uni   = ap + a1 - inter;
                    best = fmaxf(best, inter * __builtin_amdgcn_rcpf(fmaxf(uni, 1e-9f)));
                }
            }
            __syncthreads();
        }

        // block max reduce
        #pragma unroll
        for (int off = 32; off >= 1; off >>= 1)
            best = fmaxf(best, __shfl_xor(best, off));
        if ((tid & 63) == 0) wmax[tid >> 6] = best;
        __syncthreads();
        if (tid == 0) {
            const float m = fmaxf(fmaxf(wmax[0], wmax[1]), fmaxf(wmax[2], wmax[3]));
            // 24-bit fixed point; m in [0,1] -> exact integer reduction later
            const unsigned int q = (unsigned int)(m * 16777216.0f + 0.5f);
            const unsigned long long v = ((unsigned long long)MAGIC << 32) | (unsigned long long)q;
            __hip_atomic_store(&slots[blk], v, __ATOMIC_RELAXED, __HIP_MEMORY_SCOPE_AGENT);
        }
    } else {
        // ---------------- union max + finalize block ----------------
        __shared__ float pmax[4];
        float mp = -INFINITY;
        #pragma unroll
        for (int s = 0; s < UU / (256 * 4); ++s) {          // 4 sub-steps
            const int i = s * 256 + tid;
            const int4   c = union_classes4[i];
            const float4 v = union_scores4[i];
            if (c.x == 0) mp = fmaxf(mp, v.x);
            if (c.y == 0) mp = fmaxf(mp, v.y);
            if (c.z == 0) mp = fmaxf(mp, v.z);
            if (c.w == 0) mp = fmaxf(mp, v.w);
        }
        #pragma unroll
        for (int off = 32; off >= 1; off >>= 1)
            mp = fmaxf(mp, __shfl_xor(mp, off));
        if ((tid & 63) == 0) pmax[tid >> 6] = mp;
        __syncthreads();
        if (tid == 0)
            out[0] = fmaxf(fmaxf(pmax[0], pmax[1]), fmaxf(pmax[2], pmax[3]));

        // spin-collect the 32 handshake slots (lanes 0..31 of wave 0)
        if (tid < 32) {
            unsigned long long v;
            do {
                v = __hip_atomic_load(&slots[tid], __ATOMIC_RELAXED, __HIP_MEMORY_SCOPE_AGENT);
            } while ((unsigned int)(v >> 32) != MAGIC);
            // reset so the next execution starts from a non-magic state
            __hip_atomic_store(&slots[tid], 0ULL, __ATOMIC_RELAXED, __HIP_MEMORY_SCOPE_AGENT);

            unsigned int q = (unsigned int)v;
            // max over the 4 slices of each batch (lanes 4b..4b+3)
            q = max(q, __shfl_xor(q, 1, 4));
            q = max(q, __shfl_xor(q, 2, 4));
            // exact integer sum over 8 batch groups (order-independent)
            unsigned int total = 0;
            #pragma unroll
            for (int i = 0; i < 8; ++i)
                total += (unsigned int)__shfl((int)q, 4 * i, 64);
            if (tid == 0)
                out[1] = (float)total * (0.125f / 16777216.0f);
        }
    }
}

extern "C" void kernel_launch(void* const* d_in, const int* in_sizes, int n_in,
                              void* d_out, int out_size, void* d_ws, size_t ws_size,
                              hipStream_t stream) {
    const float4* pred_boxes    = (const float4*)d_in[0];
    // d_in[1] = pred_scores (unused by the reference result)
    const int4*   pred_classes4 = (const int4*)d_in[2];
    const float4* gt_boxes      = (const float4*)d_in[3];
    const float4* union_scores4 = (const float4*)d_in[4];
    const int4*   union_classes4= (const int4*)d_in[5];
    float* out = (float*)d_out;
    unsigned long long* slots = (unsigned long long*)d_ws;  // 32 x u64

    fused_kernel<<<NSLOT + 1, 256, 0, stream>>>(pred_boxes, pred_classes4, gt_boxes,
                                                union_scores4, union_classes4, slots, out);
}

// Round 4
// 13.068 us; speedup vs baseline: 4.1311x; 1.1393x over previous
//
#include <hip/hip_runtime.h>
#include <math.h>

#define BATCH  8
#define NPRED  4096
#define MGT    2048
#define UU     4096
#define GPB    4                    // pred-slice blocks per batch
#define NSLOT  (BATCH * GPB)        // 32 handshake slots
#define PSLICE (NPRED / GPB)        // 1024 preds per block
#define GPT    (MGT / 256)          // 8 gt boxes per thread (all gts of the batch)
#define MAGIC  0xC0FFEE00u

__global__ __launch_bounds__(256) void fused_kernel(
    const float4* __restrict__ pred_boxes,     // [B*N]
    const int4*   __restrict__ pred_classes4,  // [B*N/4]
    const float4* __restrict__ gt_boxes,       // [B*M]
    const float4* __restrict__ union_scores4,  // [U/4]
    const int4*   __restrict__ union_classes4, // [U/4]
    unsigned long long* __restrict__ slots,    // ws: 32 x u64 handshake words
    float* __restrict__ out)                   // [2] = {max_prob_t, max_iou_t}
{
    const int tid = threadIdx.x;
    const int blk = blockIdx.x;

    if (blk < NSLOT) {
        // ---------- producer: (batch b) x (pred slice psub) vs ALL gts of b ----------
        __shared__ float4 plist[PSLICE];     // worst-case all-person slice
        __shared__ float  parea[PSLICE];
        __shared__ int    lcount;
        __shared__ float  wmax[4];

        const int b    = blk >> 2;
        const int psub = blk & 3;

        // ---- issue ALL loads up front (13 independent vmem ops, one latency hop) ----
        const int  cbase = b * (NPRED / 4) + psub * (PSLICE / 4) + tid;  // int4 idx
        const int4 cl    = pred_classes4[cbase];
        const int  pb    = cbase * 4;                                    // float4 idx
        const float4 bx0 = pred_boxes[pb + 0];
        const float4 bx1 = pred_boxes[pb + 1];
        const float4 bx2 = pred_boxes[pb + 2];
        const float4 bx3 = pred_boxes[pb + 3];

        float4 g[GPT];
        #pragma unroll
        for (int k = 0; k < GPT; ++k)
            g[k] = gt_boxes[b * MGT + k * 256 + tid];

        float ga[GPT];
        #pragma unroll
        for (int k = 0; k < GPT; ++k)
            ga[k] = (g[k].z - g[k].x) * (g[k].w - g[k].y);   // zeroed invalid gts -> area 0 -> iou 0

        if (tid == 0) lcount = 0;
        __syncthreads();

        // ---- compact person preds (boxes already in registers, no dependent gather) ----
        if (cl.x == 0) { int p = atomicAdd(&lcount, 1); plist[p] = bx0; parea[p] = (bx0.z - bx0.x) * (bx0.w - bx0.y); }
        if (cl.y == 0) { int p = atomicAdd(&lcount, 1); plist[p] = bx1; parea[p] = (bx1.z - bx1.x) * (bx1.w - bx1.y); }
        if (cl.z == 0) { int p = atomicAdd(&lcount, 1); plist[p] = bx2; parea[p] = (bx2.z - bx2.x) * (bx2.w - bx2.y); }
        if (cl.w == 0) { int p = atomicAdd(&lcount, 1); plist[p] = bx3; parea[p] = (bx3.z - bx3.x) * (bx3.w - bx3.y); }
        __syncthreads();

        // ---- IoU: each thread's 8 gts vs the ~13 compacted persons ----
        const int cnt = lcount;              // uniform -> LDS broadcast reads below
        float best[GPT];
        #pragma unroll
        for (int k = 0; k < GPT; ++k) best[k] = 0.0f;

        for (int j = 0; j < cnt; ++j) {
            const float4 p  = plist[j];
            const float  ap = parea[j];
            #pragma unroll
            for (int k = 0; k < GPT; ++k) {
                float iw = fminf(p.z, g[k].z) - fmaxf(p.x, g[k].x);
                float ih = fminf(p.w, g[k].w) - fmaxf(p.y, g[k].y);
                iw = fmaxf(iw, 0.0f); ih = fmaxf(ih, 0.0f);
                const float inter = iw * ih;
                const float uni   = ap + ga[k] - inter;
                best[k] = fmaxf(best[k], inter * __builtin_amdgcn_rcpf(fmaxf(uni, 1e-9f)));
            }
        }

        float bestv = best[0];
        #pragma unroll
        for (int k = 1; k < GPT; ++k) bestv = fmaxf(bestv, best[k]);

        // block max reduce
        #pragma unroll
        for (int off = 32; off >= 1; off >>= 1)
            bestv = fmaxf(bestv, __shfl_xor(bestv, off));
        if ((tid & 63) == 0) wmax[tid >> 6] = bestv;
        __syncthreads();
        if (tid == 0) {
            const float m = fmaxf(fmaxf(wmax[0], wmax[1]), fmaxf(wmax[2], wmax[3]));
            // iou >= 0 -> raw float bits are uint-monotone; exact, no quantization
            const unsigned long long v =
                ((unsigned long long)MAGIC << 32) | (unsigned long long)__float_as_uint(m);
            __hip_atomic_store(&slots[blk], v, __ATOMIC_RELAXED, __HIP_MEMORY_SCOPE_AGENT);
        }
    } else {
        // ---------------- finalizer: union masked max (parallel) + collect ----------------
        __shared__ float pmax[4];
        float mp = -INFINITY;
        #pragma unroll
        for (int s = 0; s < UU / (256 * 4); ++s) {        // 4 sub-steps
            const int i = s * 256 + tid;
            const int4   c = union_classes4[i];
            const float4 v = union_scores4[i];
            if (c.x == 0) mp = fmaxf(mp, v.x);
            if (c.y == 0) mp = fmaxf(mp, v.y);
            if (c.z == 0) mp = fmaxf(mp, v.z);
            if (c.w == 0) mp = fmaxf(mp, v.w);
        }
        #pragma unroll
        for (int off = 32; off >= 1; off >>= 1)
            mp = fmaxf(mp, __shfl_xor(mp, off));
        if ((tid & 63) == 0) pmax[tid >> 6] = mp;
        __syncthreads();
        if (tid == 0)
            out[0] = fmaxf(fmaxf(pmax[0], pmax[1]), fmaxf(pmax[2], pmax[3]));

        // spin-collect the 32 handshake slots (lanes 0..31 of wave 0)
        if (tid < 32) {
            unsigned long long v;
            do {
                v = __hip_atomic_load(&slots[tid], __ATOMIC_RELAXED, __HIP_MEMORY_SCOPE_AGENT);
            } while ((unsigned int)(v >> 32) != MAGIC);
            // reset so the next execution (graph replay) starts from a non-magic state
            __hip_atomic_store(&slots[tid], 0ULL, __ATOMIC_RELAXED, __HIP_MEMORY_SCOPE_AGENT);

            unsigned int q = (unsigned int)v;             // raw float bits, iou >= 0
            // max over the 4 pred-slices of each batch (lanes 4b..4b+3)
            q = max(q, (unsigned int)__shfl_xor((int)q, 1, 4));
            q = max(q, (unsigned int)__shfl_xor((int)q, 2, 4));
            // fixed-order sum over the 8 batch maxima -> deterministic
            float s = 0.0f;
            #pragma unroll
            for (int i = 0; i < 8; ++i)
                s += __uint_as_float((unsigned int)__shfl((int)q, 4 * i, 64));
            if (tid == 0)
                out[1] = s * 0.125f;                      // mean over batches
        }
    }
}

extern "C" void kernel_launch(void* const* d_in, const int* in_sizes, int n_in,
                              void* d_out, int out_size, void* d_ws, size_t ws_size,
                              hipStream_t stream) {
    const float4* pred_boxes    = (const float4*)d_in[0];
    // d_in[1] = pred_scores (unused by the reference result)
    const int4*   pred_classes4 = (const int4*)d_in[2];
    const float4* gt_boxes      = (const float4*)d_in[3];
    const float4* union_scores4 = (const float4*)d_in[4];
    const int4*   union_classes4= (const int4*)d_in[5];
    float* out = (float*)d_out;
    unsigned long long* slots = (unsigned long long*)d_ws;  // 32 x u64

    fused_kernel<<<NSLOT + 1, 256, 0, stream>>>(pred_boxes, pred_classes4, gt_boxes,
                                                union_scores4, union_classes4, slots, out);
}

// Round 5
// 11.252 us; speedup vs baseline: 4.7981x; 1.1614x over previous
//
#include <hip/hip_runtime.h>
#include <math.h>

#define BATCH  8
#define NPRED  4096
#define MGT    2048
#define UU     4096
#define SPB    8                     // pred-slice blocks per batch
#define NSLOT  (BATCH * SPB)         // 64 producer blocks / handshake slots
#define PSLICE (NPRED / SPB)         // 512 preds per block
#define GPT    (MGT / 256)           // 8 gt boxes per thread (all gts of the batch)
#define MAGIC  0xC0FFEE00u
#define SLOT_STRIDE 16               // 16 x u64 = 128 B: one cache line per slot

__global__ __launch_bounds__(256) void fused_kernel(
    const float4* __restrict__ pred_boxes,     // [B*N]
    const int2*   __restrict__ pred_classes2,  // [B*N/2]
    const float4* __restrict__ gt_boxes,       // [B*M]
    const float4* __restrict__ union_scores4,  // [U/4]
    const int4*   __restrict__ union_classes4, // [U/4]
    unsigned long long* __restrict__ slots,    // ws: NSLOT lines, 128 B apart
    float* __restrict__ out)                   // [2] = {max_prob_t, max_iou_t}
{
    const int tid = threadIdx.x;
    const int blk = blockIdx.x;

    if (blk < NSLOT) {
        // ---------- producer: (batch b, pred slice psub) vs ALL gts of b ----------
        __shared__ float4 plist[PSLICE];     // worst-case all-person slice
        __shared__ float  parea[PSLICE];
        __shared__ int    lcount;
        __shared__ float  wmax[4];

        const int b    = blk >> 3;
        const int psub = blk & 7;

        // ---- issue ALL loads up front (11 independent vmem ops, one latency hop) ----
        const int  cbase = b * (NPRED / 2) + psub * (PSLICE / 2) + tid;  // int2 idx
        const int2 cl    = pred_classes2[cbase];
        const int  pb    = cbase * 2;                                    // float4 idx
        const float4 bx0 = pred_boxes[pb + 0];
        const float4 bx1 = pred_boxes[pb + 1];

        float4 g[GPT];
        #pragma unroll
        for (int k = 0; k < GPT; ++k)
            g[k] = gt_boxes[b * MGT + k * 256 + tid];

        float ga[GPT];
        #pragma unroll
        for (int k = 0; k < GPT; ++k)
            ga[k] = (g[k].z - g[k].x) * (g[k].w - g[k].y);  // zeroed invalid gt -> iou 0

        if (tid == 0) lcount = 0;
        __syncthreads();

        // ---- compact person preds (boxes already in registers) ----
        if (cl.x == 0) { int p = atomicAdd(&lcount, 1); plist[p] = bx0; parea[p] = (bx0.z - bx0.x) * (bx0.w - bx0.y); }
        if (cl.y == 0) { int p = atomicAdd(&lcount, 1); plist[p] = bx1; parea[p] = (bx1.z - bx1.x) * (bx1.w - bx1.y); }
        __syncthreads();

        // ---- IoU: this thread's 8 gts vs the ~6 compacted persons ----
        const int cnt = lcount;              // uniform -> LDS broadcast reads
        float best[GPT];
        #pragma unroll
        for (int k = 0; k < GPT; ++k) best[k] = 0.0f;

        for (int j = 0; j < cnt; ++j) {
            const float4 p  = plist[j];
            const float  ap = parea[j];
            #pragma unroll
            for (int k = 0; k < GPT; ++k) {
                float iw = fminf(p.z, g[k].z) - fmaxf(p.x, g[k].x);
                float ih = fminf(p.w, g[k].w) - fmaxf(p.y, g[k].y);
                iw = fmaxf(iw, 0.0f); ih = fmaxf(ih, 0.0f);
                const float inter = iw * ih;
                const float uni   = ap + ga[k] - inter;
                best[k] = fmaxf(best[k], inter * __builtin_amdgcn_rcpf(fmaxf(uni, 1e-9f)));
            }
        }

        float bestv = best[0];
        #pragma unroll
        for (int k = 1; k < GPT; ++k) bestv = fmaxf(bestv, best[k]);

        // block max reduce
        #pragma unroll
        for (int off = 32; off >= 1; off >>= 1)
            bestv = fmaxf(bestv, __shfl_xor(bestv, off));
        if ((tid & 63) == 0) wmax[tid >> 6] = bestv;
        __syncthreads();
        if (tid == 0) {
            const float m = fmaxf(fmaxf(wmax[0], wmax[1]), fmaxf(wmax[2], wmax[3]));
            // iou >= 0 -> raw float bits are uint-monotone; exact payload
            const unsigned long long v =
                ((unsigned long long)MAGIC << 32) | (unsigned long long)__float_as_uint(m);
            __hip_atomic_store(&slots[blk * SLOT_STRIDE], v,
                               __ATOMIC_RELAXED, __HIP_MEMORY_SCOPE_AGENT);
        }
    } else {
        // ---------- finalizer: union masked max (overlaps producers), then collect ----------
        __shared__ float pmax[4];
        float mp = -INFINITY;
        #pragma unroll
        for (int s = 0; s < UU / (256 * 4); ++s) {          // 4 sub-steps
            const int i = s * 256 + tid;
            const int4   c = union_classes4[i];
            const float4 v = union_scores4[i];
            if (c.x == 0) mp = fmaxf(mp, v.x);
            if (c.y == 0) mp = fmaxf(mp, v.y);
            if (c.z == 0) mp = fmaxf(mp, v.z);
            if (c.w == 0) mp = fmaxf(mp, v.w);
        }
        #pragma unroll
        for (int off = 32; off >= 1; off >>= 1)
            mp = fmaxf(mp, __shfl_xor(mp, off));
        if ((tid & 63) == 0) pmax[tid >> 6] = mp;
        __syncthreads();
        if (tid == 0)
            out[0] = fmaxf(fmaxf(pmax[0], pmax[1]), fmaxf(pmax[2], pmax[3]));

        // wave 0: lane l polls its own 128B-padded slot (1 writer + 1 reader per line)
        if (tid < 64) {
            unsigned long long v;
            do {
                v = __hip_atomic_load(&slots[tid * SLOT_STRIDE],
                                      __ATOMIC_RELAXED, __HIP_MEMORY_SCOPE_AGENT);
            } while ((unsigned int)(v >> 32) != MAGIC);
            // reset so the next replay starts from a non-magic state
            __hip_atomic_store(&slots[tid * SLOT_STRIDE], 0ULL,
                               __ATOMIC_RELAXED, __HIP_MEMORY_SCOPE_AGENT);

            unsigned int q = (unsigned int)v;               // raw float bits, iou >= 0
            // max over the 8 pred-slices of each batch (lanes 8b..8b+7)
            q = max(q, (unsigned int)__shfl_xor((int)q, 1, 8));
            q = max(q, (unsigned int)__shfl_xor((int)q, 2, 8));
            q = max(q, (unsigned int)__shfl_xor((int)q, 4, 8));
            // fixed-order sum over the 8 batch maxima -> bitwise deterministic
            float s = 0.0f;
            #pragma unroll
            for (int i = 0; i < 8; ++i)
                s += __uint_as_float((unsigned int)__shfl((int)q, 8 * i, 64));
            if (tid == 0)
                out[1] = s * 0.125f;                        // mean over batches
        }
    }
}

extern "C" void kernel_launch(void* const* d_in, const int* in_sizes, int n_in,
                              void* d_out, int out_size, void* d_ws, size_t ws_size,
                              hipStream_t stream) {
    const float4* pred_boxes    = (const float4*)d_in[0];
    // d_in[1] = pred_scores (unused by the reference result)
    const int2*   pred_classes2 = (const int2*)d_in[2];
    const float4* gt_boxes      = (const float4*)d_in[3];
    const float4* union_scores4 = (const float4*)d_in[4];
    const int4*   union_classes4= (const int4*)d_in[5];
    float* out = (float*)d_out;
    unsigned long long* slots = (unsigned long long*)d_ws;  // 64 x 128 B lines

    fused_kernel<<<NSLOT + 1, 256, 0, stream>>>(pred_boxes, pred_classes2, gt_boxes,
                                                union_scores4, union_classes4, slots, out);
}